// Round 1
// baseline (38.142 us; speedup 1.0000x reference)
//
#include <hip/hip_runtime.h>

#define BATCH  16
#define LEN    512
#define NSTATE 64
#define DMODEL 256
#define TB     32      // time-batch between LDS transpose-reduces
#define WAVES  4       // waves per block

__global__ __launch_bounds__(WAVES * 64, 4)
void s4d_scan_kernel(const float* __restrict__ u,
                     const float* __restrict__ Lre_p, const float* __restrict__ Lim_p,
                     const float* __restrict__ Bre_p, const float* __restrict__ Bim_p,
                     const float* __restrict__ Pre_p, const float* __restrict__ Pim_p,
                     const float* __restrict__ logdt_p,
                     float* __restrict__ y)
{
    // [wave][state row][time col + pad] : write (lane*33+tau)&31 -> 2-way (free)
    // read ((32h+j)*33 + tl)&31 = (j+tl)&31 -> 2-way (free)
    __shared__ float cb[WAVES][NSTATE][TB + 1];   // ~33.8 KB

    const int tid  = threadIdx.x;
    const int lane = tid & 63;
    const int widx = tid >> 6;
    const int wid  = blockIdx.x * WAVES + widx;   // 0..4095
    const int b    = wid >> 8;                    // / DMODEL
    const int d    = wid & 255;                   // % DMODEL

    // ---- per-lane (state n = lane) coefficients --------------------------
    const float dt  = expf(logdt_p[0]);
    const float Lre = Lre_p[lane];
    const float Lim = Lim_p[lane];
    const float eL  = expf(Lre);
    // w = -exp(Lambda):  a = exp(dt*w)
    const float wre = -eL * cosf(Lim);
    const float wim = -eL * sinf(Lim);
    const float mag = expf(dt * wre);
    const float are = mag * cosf(dt * wim);
    const float aim = mag * sinf(dt * wim);
    const float Bdre = dt * Bre_p[lane];
    const float Bdim = dt * Bim_p[lane];
    const float Pre  = Pre_p[lane * DMODEL + d];
    const float Pim  = Pim_p[lane * DMODEL + d];
    // G = C * Bd  (fold output projection into the input matrix)
    const float Gre = Pre * Bdre - Pim * Bdim;
    const float Gim = Pre * Bdim + Pim * Bdre;

    float zre = 0.f, zim = 0.f;   // z = C * x  (complex, per state)

    const float* up = u + (size_t)b * LEN * DMODEL + d;   // + t*DMODEL
    float*       yp = y + (size_t)b * LEN * DMODEL + d;

    const int tl = lane & 31;     // time slot within batch (loads & reduce col)
    const int h  = lane >> 5;     // which half of states this lane reduces

    for (int t0 = 0; t0 < LEN; t0 += TB) {
        // stage this batch's u into registers (lanes 0..31 hold valid slots;
        // lanes 32..63 redundantly load the same — readlane only uses 0..31)
        const float ureg = up[(t0 + tl) * DMODEL];

        #pragma unroll
        for (int tau = 0; tau < TB; ++tau) {
            // broadcast u[b, t0+tau, d] from lane tau (compile-time index)
            const float us = __uint_as_float(
                __builtin_amdgcn_readlane(__float_as_uint(ureg), tau));
            // z = a*z + G*u   (complex FMA, 6 VALU)
            const float nzre = fmaf(are, zre, fmaf(-aim, zim, Gre * us));
            const float nzim = fmaf(are, zim, fmaf( aim, zre, Gim * us));
            zre = nzre;
            zim = nzim;
            cb[widx][lane][tau] = zre;     // contribution of state `lane` at time tau
        }
        __syncthreads();

        // transpose-reduce: lane (h, tl) sums states 32h..32h+31 at time tl
        float s = 0.f;
        #pragma unroll
        for (int j = 0; j < 32; ++j)
            s += cb[widx][32 * h + j][tl];
        s += __shfl_xor(s, 32, 64);        // combine the two state-halves
        if (lane < 32)
            yp[(t0 + tl) * DMODEL] = s;
        __syncthreads();                    // protect cb before next batch's writes
    }
}

extern "C" void kernel_launch(void* const* d_in, const int* in_sizes, int n_in,
                              void* d_out, int out_size, void* d_ws, size_t ws_size,
                              hipStream_t stream) {
    const float* u      = (const float*)d_in[0];
    const float* Lre    = (const float*)d_in[1];
    const float* Lim    = (const float*)d_in[2];
    const float* Bre    = (const float*)d_in[3];
    const float* Bim    = (const float*)d_in[4];
    const float* Pre    = (const float*)d_in[5];
    const float* Pim    = (const float*)d_in[6];
    const float* logdt  = (const float*)d_in[7];
    float* y = (float*)d_out;

    const int nblocks = (BATCH * DMODEL) / WAVES;   // 1024
    s4d_scan_kernel<<<nblocks, WAVES * 64, 0, stream>>>(
        u, Lre, Lim, Bre, Bim, Pre, Pim, logdt, y);
}